// Round 9
// baseline (144.702 us; speedup 1.0000x reference)
//
#include <hip/hip_runtime.h>
#include <hip/hip_bf16.h>
#include <cstdint>

typedef __bf16 bf16;
typedef __bf16 bf16x4 __attribute__((ext_vector_type(4)));
typedef __bf16 bf16x8 __attribute__((ext_vector_type(8)));
typedef float floatx4 __attribute__((ext_vector_type(4)));

typedef __attribute__((address_space(1))) void as1_void;
typedef __attribute__((address_space(3))) void as3_void;

// async global->LDS, 16B per lane. LDS dest must be wave-uniform base + lane*16.
__device__ __forceinline__ void gld16(const void* g, void* l) {
#if __has_builtin(__builtin_amdgcn_global_load_lds)
  __builtin_amdgcn_global_load_lds((as1_void*)(uintptr_t)g, (as3_void*)l, 16, 0, 0);
#else
  *(uint4*)l = *(const uint4*)g;
#endif
}

// ---------------- fp32 -> bf16 conversion (x, Wq|Wk|Wv concat, Wo) -------------
__global__ __launch_bounds__(256) void convert_kernel(
    const float* __restrict__ x, const float* __restrict__ wq,
    const float* __restrict__ wk, const float* __restrict__ wv,
    const float* __restrict__ wo, bf16* __restrict__ xbf,
    bf16* __restrict__ wqkv, bf16* __restrict__ wob) {
  int i = blockIdx.x * 256 + threadIdx.x;  // one float4 (4 elems) per thread
  const float* src;
  bf16* dst;
  int off;
  if (i < 1048576) {            // x: 4,194,304 elems
    src = x; dst = xbf; off = i;
  } else if (i < 1310720) {     // Wq
    src = wq; dst = wqkv; off = i - 1048576;
  } else if (i < 1572864) {     // Wk
    src = wk; dst = wqkv + 1048576; off = i - 1310720;
  } else if (i < 1835008) {     // Wv
    src = wv; dst = wqkv + 2097152; off = i - 1572864;
  } else {                      // Wo
    src = wo; dst = wob; off = i - 1835008;
  }
  float4 v = ((const float4*)src)[off];
  bf16x4 o;
  o[0] = (bf16)v.x; o[1] = (bf16)v.y; o[2] = (bf16)v.z; o[3] = (bf16)v.w;
  ((bf16x4*)dst)[off] = o;
}

// ---------------- 256x192 8-phase NT GEMM (T2+T3+T4+T5), bf16 out --------------
// Tile 256(M) x 192(N), BK=64 -> grid (16,16) = 256 blocks = EXACTLY 1/CU.
// 512 threads = 8 waves (2M x 4N), wave tile 128 x 48 (3 n-frags).
// LDS 112 KiB: buf{0,1} x [A 32K (4 units) | B 24K (3 units)]; a staging UNIT
// is 64 rows x 64 cols bf16 = 8 KiB = 1 gld16/thread. Swizzle: byte col slot s
// at row r holds global chunk s^(r&7), write-side on the global source and
// read-side on ds_read.
// Liveness ledger (buf0 tile T): B last read ph2, A last read ph3 ->
//   (T+2).B staged ph3/ph4, (T+2).A staged ph5..ph7; buf1: B last ph6, A ph7
//   -> (T+3).B0 ph7, rest ph8; (T+1).A1/A3 staged ph1/ph2.
// W1 (end ph4): vmcnt(3); final iter vmcnt(0). W2 (end ph8): vmcnt(5).
// R9: 2-D XCD chunk (XCD c owns by in [4(c>>1),+4) x bx in [8(c&1),+8)):
//   per-XCD footprint = 4 A-panels (2MB) + 8 B-panels (3MB) -- mostly
//   L2-resident, cuts GEMM1's L3 reads ~70 -> ~45MB. Pure bijective work
//   permutation (c=nid&7 matches HW XCD round-robin on dispatch order).
//   NOTE: R2's negative swizzle result was a 1-D chunk bundled with lgkm
//   pacing; this is the isolated 2-D test.
#define BAR asm volatile("s_barrier" ::: "memory")
#define LGKM0                                         \
  do {                                                \
    asm volatile("s_waitcnt lgkmcnt(0)" ::: "memory");\
    __builtin_amdgcn_sched_barrier(0);                \
  } while (0)

// stage one 64x64 unit of operand op (0=A,1=B), unit u, K-tile t, into buf
#define STAGEU(buf, op, u, t)                                                  \
  gld16(((op) ? Bb : Ab) + (size_t)(u) * 64 * Kb + (size_t)(t) * 128 + rowOff, \
        lds + (buf) * 57344 + (op) * 32768 + (u) * 8192 + tid * 16)

#define LDA_(buf, mh)                                                          \
  do {                                                                         \
    _Pragma("unroll") for (int q = 0; q < 4; ++q)                              \
      _Pragma("unroll") for (int ks = 0; ks < 2; ++ks)                         \
        aR[q][ks] = *(const bf16x8*)(lds + (buf) * 57344 +                     \
            (wm * 2 + (mh)) * 8192 + (q * 16 + n0) * 128 +                     \
            ((ks * 64 + quad * 16) ^ swz));                                    \
  } while (0)

#define LDB_(buf, g)                                                           \
  do {                                                                         \
    _Pragma("unroll") for (int j = 0; j < ((g) ? 1 : 2); ++j)                  \
      _Pragma("unroll") for (int ks = 0; ks < 2; ++ks) {                       \
        const int ni_ = (g) ? 2 : j;                                           \
        const int row_ = wn * 48 + ni_ * 16 + n0;                              \
        bR[ni_][ks] = *(const bf16x8*)(lds + (buf) * 57344 + 32768 +           \
            (row_ >> 6) * 8192 + (row_ & 63) * 128 +                           \
            ((ks * 64 + quad * 16) ^ swz));                                    \
      }                                                                        \
  } while (0)

#define MMg0(mh)                                                               \
  do {                                                                         \
    __builtin_amdgcn_s_setprio(1);                                             \
    _Pragma("unroll") for (int q = 0; q < 4; ++q)                              \
      _Pragma("unroll") for (int j = 0; j < 2; ++j)                            \
        _Pragma("unroll") for (int ks = 0; ks < 2; ++ks)                       \
          acc[(mh) * 4 + q][j] = __builtin_amdgcn_mfma_f32_16x16x32_bf16(      \
              aR[q][ks], bR[j][ks], acc[(mh) * 4 + q][j], 0, 0, 0);            \
    __builtin_amdgcn_s_setprio(0);                                             \
  } while (0)

#define MMg1(mh)                                                               \
  do {                                                                         \
    __builtin_amdgcn_s_setprio(1);                                             \
    _Pragma("unroll") for (int q = 0; q < 4; ++q)                              \
      _Pragma("unroll") for (int ks = 0; ks < 2; ++ks)                         \
        acc[(mh) * 4 + q][2] = __builtin_amdgcn_mfma_f32_16x16x32_bf16(        \
            aR[q][ks], bR[2][ks], acc[(mh) * 4 + q][2], 0, 0, 0);              \
    __builtin_amdgcn_s_setprio(0);                                             \
  } while (0)

__global__ __launch_bounds__(512, 2) void gemm192_nt(
    const bf16* __restrict__ A, const bf16* __restrict__ Bm,
    bf16* __restrict__ C, int M, int N, int K) {
  __shared__ __attribute__((aligned(16))) char lds[114688];
  const int tid = threadIdx.x;
  const int lane = tid & 63, wave = tid >> 6;
  const int quad = lane >> 4, n0 = lane & 15;
  const int wm = wave >> 2, wn = wave & 3;
  const int swz = (n0 & 7) << 4;
  const size_t Kb = (size_t)K * 2;  // row stride in bytes
  // 2-D XCD chunk (only for the 16x16 grid this kernel is launched with):
  // XCD c = nid&7 (HW round-robin over dispatch order), local l = nid>>3.
  int by, bx;
  if (gridDim.x == 16 && gridDim.y == 16) {
    const int nid = blockIdx.y * gridDim.x + blockIdx.x;
    const int c = nid & 7, l = nid >> 3;
    by = (c >> 1) * 4 + (l >> 3);   // 4 consecutive A-panels per XCD
    bx = (c & 1) * 8 + (l & 7);     // 8 B-panels per XCD
  } else {
    by = blockIdx.y; bx = blockIdx.x;
  }
  const char* Ab = (const char*)(A + (size_t)by * 256 * K);
  const char* Bb = (const char*)(Bm + (size_t)bx * 192 * K);
  const int srow = tid >> 3;
  const size_t rowOff = (size_t)srow * Kb + (size_t)(16 * ((tid & 7) ^ (srow & 7)));

  floatx4 acc[8][3] = {};
  bf16x8 aR[4][2];     // current A m-half (4 m-frags x 2 k-steps)
  bf16x8 bR[3][2];     // all 3 n-frags x 2 k-steps

  const int NT = K >> 6;   // 64-wide K-tiles (even)
  const int NI = K >> 7;   // iterations (2 tiles each)

  // prologue: tile0 full (7 units) -> buf0; tile1 {B0,B1,B2,A0,A2} -> buf1
  STAGEU(0, 0, 0, 0); STAGEU(0, 0, 1, 0); STAGEU(0, 0, 2, 0); STAGEU(0, 0, 3, 0);
  STAGEU(0, 1, 0, 0); STAGEU(0, 1, 1, 0); STAGEU(0, 1, 2, 0);
  STAGEU(1, 1, 0, 1); STAGEU(1, 1, 1, 1); STAGEU(1, 1, 2, 1);
  STAGEU(1, 0, 0, 1); STAGEU(1, 0, 2, 1);
  asm volatile("s_waitcnt vmcnt(5)" ::: "memory");  // tile0's 7 units landed
  BAR;

  for (int i = 0; i < NI; ++i) {
    const int T = 2 * i;
    const bool s2 = (T + 2 < NT);   // == s3 (NT even)
    // ---- K-tile T from buf0 ----
    LDB_(0, 0); LDA_(0, 0);
    STAGEU(1, 0, 1, T + 1);                               // (T+1).A1
    BAR; LGKM0; MMg0(0); BAR;
    LDB_(0, 1);
    STAGEU(1, 0, 3, T + 1);                               // (T+1).A3
    BAR; LGKM0; MMg1(0); BAR;
    LDA_(0, 1);
    if (s2) { STAGEU(0, 1, 0, T + 2); STAGEU(0, 1, 1, T + 2); }  // (T+2).B0,B1
    BAR; LGKM0; MMg0(1); BAR;
    if (s2) STAGEU(0, 1, 2, T + 2);                       // (T+2).B2
    BAR; MMg1(1);
    if (i + 1 < NI) { asm volatile("s_waitcnt vmcnt(3)" ::: "memory"); }
    else            { asm volatile("s_waitcnt vmcnt(0)" ::: "memory"); }
    BAR;
    // ---- K-tile T+1 from buf1 ----
    LDB_(1, 0); LDA_(1, 0);
    if (s2) { STAGEU(0, 0, 0, T + 2); STAGEU(0, 0, 2, T + 2); }  // (T+2).A0,A2
    BAR; LGKM0; MMg0(0); BAR;
    LDB_(1, 1);
    if (s2) STAGEU(0, 0, 1, T + 2);                       // (T+2).A1
    BAR; LGKM0; MMg1(0); BAR;
    LDA_(1, 1);
    if (s2) { STAGEU(0, 0, 3, T + 2); STAGEU(1, 1, 0, T + 3); }  // (T+2).A3,(T+3).B0
    BAR; LGKM0; MMg0(1); BAR;
    if (s2) { STAGEU(1, 1, 1, T + 3); STAGEU(1, 1, 2, T + 3);    // (T+3).B1,B2
              STAGEU(1, 0, 0, T + 3); STAGEU(1, 0, 2, T + 3); }  // (T+3).A0,A2
    BAR; MMg1(1);
    asm volatile("s_waitcnt vmcnt(5)" ::: "memory");
    BAR;
  }

  const int rowBase = by * 256 + wm * 128 + quad * 4;
  const int colBase = bx * 192 + wn * 48 + n0;
#pragma unroll
  for (int mi = 0; mi < 8; ++mi)
#pragma unroll
    for (int ni = 0; ni < 3; ++ni)
#pragma unroll
      for (int r = 0; r < 4; ++r)
        C[(size_t)(rowBase + mi * 16 + r) * N + colBase + ni * 16] =
            (bf16)acc[mi][ni][r];
}

#undef STAGEU
#undef LDA_
#undef LDB_
#undef MMg0
#undef MMg1

// ---------------- 128x128 4-phase NT GEMM, fp32+bias out (output proj) ---------
// Tile 128x128, BK=64 -> grid (8,32) = 256 blocks = 1/CU. 512 threads = 8 waves
// (2M x 4N), wave tile 64x32. 4 phases/iteration (2 per K-tile, 8 MFMA each),
// counted-vmcnt discipline. Verified R8 (143.0 us total, refcheck passed).
// Liveness ledger (unit = 64x64 = 8 KiB = 1 gld16/thread):
//   reads: ph1 {B0,B1 frags + A mh0}, MM(mh0); ph2 {A mh1}, MM(mh1).
//   stages: ph1 (T+1).{A0,A1,B1}; ph2 (T+2).{B0,B1}; ph3 (T+2).{A0,A1};
//           ph4 (T+3).{B0}.
//   W1 (end ph2): vmcnt(2) proves (T+1) landed (final iter: vmcnt(0)).
//   W2 (end ph4): vmcnt(1) proves (T+2) landed.
//   Prologue: 5 ops; vmcnt(1). NT=16 even -> s2 == s3.
// XCD-chunk: 32 ids/XCD = {4 A-panels (1MB) + whole wob (2MB)} = 3MB < L2.
#define STAGE2(buf, op, u, t)                                                  \
  gld16(((op) ? Bb : Ab) + (size_t)(u) * 64 * Kb + (size_t)(t) * 128 + rowOff, \
        lds + (buf) * 32768 + (op) * 16384 + (u) * 8192 + tid * 16)

#define LDA2(buf, mh)                                                          \
  do {                                                                         \
    _Pragma("unroll") for (int qq = 0; qq < 2; ++qq)                           \
      _Pragma("unroll") for (int ks = 0; ks < 2; ++ks)                         \
        aR[qq][ks] = *(const bf16x8*)(lds + (buf) * 32768 + wm * 8192 +        \
            (((mh) * 2 + qq) * 16 + n0) * 128 + ((ks * 64 + quad * 16) ^ swz));\
  } while (0)

#define LDB2(buf, j)                                                           \
  do {                                                                         \
    _Pragma("unroll") for (int ks = 0; ks < 2; ++ks)                           \
      bR[j][ks] = *(const bf16x8*)(lds + (buf) * 32768 + 16384 +               \
          (wn >> 1) * 8192 + ((wn & 1) * 32 + (j) * 16 + n0) * 128 +           \
          ((ks * 64 + quad * 16) ^ swz));                                      \
  } while (0)

#define MM2(mh, nh)                                                            \
  do {                                                                         \
    __builtin_amdgcn_s_setprio(1);                                             \
    _Pragma("unroll") for (int qq = 0; qq < 2; ++qq)                           \
      _Pragma("unroll") for (int ks = 0; ks < 2; ++ks)                         \
        acc[(mh) * 2 + qq][nh] = __builtin_amdgcn_mfma_f32_16x16x32_bf16(      \
            aR[qq][ks], bR[nh][ks], acc[(mh) * 2 + qq][nh], 0, 0, 0);          \
    __builtin_amdgcn_s_setprio(0);                                             \
  } while (0)

__global__ __launch_bounds__(512, 2) void gemm128_nt(
    const bf16* __restrict__ A, const bf16* __restrict__ Bm,
    float* __restrict__ Cf, const float* __restrict__ bias,
    int M, int N, int K) {
  __shared__ __attribute__((aligned(16))) char lds[65536];
  const int tid = threadIdx.x;
  const int lane = tid & 63, wave = tid >> 6;
  const int quad = lane >> 4, n0 = lane & 15;
  const int wm = wave >> 2, wn = wave & 3;
  const int swz = (n0 & 7) << 4;
  const size_t Kb = (size_t)K * 2;
  // XCD-chunked bijective swizzle (nwg = 256, multiple of 8)
  const int nwg = gridDim.x * gridDim.y;
  const int nid = blockIdx.y * gridDim.x + blockIdx.x;
  int sid = nid;
  if ((nwg & 7) == 0) sid = (nid & 7) * (nwg >> 3) + (nid >> 3);
  const int bx = sid % gridDim.x, by = sid / gridDim.x;
  const char* Ab = (const char*)(A + (size_t)by * 128 * K);
  const char* Bb = (const char*)(Bm + (size_t)bx * 128 * K);
  const int srow = tid >> 3;
  const size_t rowOff = (size_t)srow * Kb + (size_t)(16 * ((tid & 7) ^ (srow & 7)));

  floatx4 acc[4][2] = {};
  bf16x8 aR[2][2];   // current m-half frags (2 q x 2 ks)
  bf16x8 bR[2][2];   // both n-frags x 2 ks

  const int NT = K >> 6;   // 16
  const int NI = K >> 7;   // 8

  // prologue: tile0 {A0,A1,B0,B1} -> buf0; tile1 {B0} -> buf1
  STAGE2(0, 0, 0, 0); STAGE2(0, 0, 1, 0); STAGE2(0, 1, 0, 0); STAGE2(0, 1, 1, 0);
  STAGE2(1, 1, 0, 1);
  asm volatile("s_waitcnt vmcnt(1)" ::: "memory");  // tile0 landed
  BAR;

  for (int i = 0; i < NI; ++i) {
    const int T = 2 * i;
    const bool s2 = (T + 2 < NT);   // == s3 (NT even)
    // ---- K-tile T from buf0 (2 fat phases) ----
    LDB2(0, 0); LDB2(0, 1); LDA2(0, 0);
    STAGE2(1, 0, 0, T + 1); STAGE2(1, 0, 1, T + 1);   // (T+1).A0,A1
    STAGE2(1, 1, 1, T + 1);                           // (T+1).B1
    BAR; LGKM0; MM2(0, 0); MM2(0, 1); BAR;
    LDA2(0, 1);
    if (s2) { STAGE2(0, 1, 0, T + 2); STAGE2(0, 1, 1, T + 2); }  // (T+2).B0,B1
    BAR; LGKM0; MM2(1, 0); MM2(1, 1);
    if (i + 1 < NI) { asm volatile("s_waitcnt vmcnt(2)" ::: "memory"); }
    else            { asm volatile("s_waitcnt vmcnt(0)" ::: "memory"); }
    BAR;
    // ---- K-tile T+1 from buf1 (2 fat phases) ----
    LDB2(1, 0); LDB2(1, 1); LDA2(1, 0);
    if (s2) { STAGE2(0, 0, 0, T + 2); STAGE2(0, 0, 1, T + 2); }  // (T+2).A0,A1
    BAR; LGKM0; MM2(0, 0); MM2(0, 1); BAR;
    LDA2(1, 1);
    if (s2) STAGE2(1, 1, 0, T + 3);                   // (T+3).B0
    BAR; LGKM0; MM2(1, 0); MM2(1, 1);
    asm volatile("s_waitcnt vmcnt(1)" ::: "memory");
    BAR;
  }

  const int rowBase = by * 128 + wm * 64 + quad * 4;
  const int colBase = bx * 128 + wn * 32 + n0;
#pragma unroll
  for (int ni = 0; ni < 2; ++ni) {
    const float badd = bias[colBase + ni * 16];
#pragma unroll
    for (int mi = 0; mi < 4; ++mi)
#pragma unroll
      for (int r = 0; r < 4; ++r)
        Cf[(size_t)(rowBase + mi * 16 + r) * N + colBase + ni * 16] =
            acc[mi][ni][r] + badd;
  }
}

#undef BAR
#undef LGKM0
#undef STAGE2
#undef LDA2
#undef LDB2
#undef MM2

// ---------------- sliding-window attention ------------------------------------
// block = (b, h, 64-query tile); 4 waves, wave w owns queries [w*16, w*16+16).
// Key window rows t=0..127 <-> j = i0-32+t; out-of-range rows are zero
// (matches reference zero-padding: score 0 participates in softmax, V adds 0).
// LDS strides chosen so every frag access is <=2 lanes/bank (free, m136):
//   Ks stride 72 (144 B), Vt stride 136 (272 B), Ps stride 136.
__global__ __launch_bounds__(256) void attn_kernel(const bf16* __restrict__ qkv,
                                                   bf16* __restrict__ aout) {
  __shared__ __attribute__((aligned(16))) bf16 Ks[128 * 72];
  __shared__ __attribute__((aligned(16))) bf16 VsPs[128 * 72];  // Vs, then Ps
  __shared__ __attribute__((aligned(16))) bf16 Vt[64 * 136];
  const int bid = blockIdx.x;
  const int b = bid >> 9;            // 512 blocks per batch (16 heads x 32 tiles)
  const int h = (bid >> 5) & 15;
  const int i0 = (bid & 31) * 64;
  const int tid = threadIdx.x;
  const int wave = tid >> 6, lane = tid & 63;
  const int quad = lane >> 4, n0 = lane & 15;
  bf16* Vs = VsPs;

  // Q fragments straight from global, issued EARLY so HBM/L2 latency hides
  // under the K/V staging + transpose (consumed only after the barriers).
  bf16x8 aq[2];
#pragma unroll
  for (int ks = 0; ks < 2; ++ks)
    aq[ks] = *(const bf16x8*)(qkv +
        (size_t)(b * 2048 + i0 + wave * 16 + n0) * 3072 + h * 64 + ks * 32 + quad * 8);

  // stage K and V windows: 128 rows x 8 16B-chunks each, zero out-of-range
#pragma unroll
  for (int it = 0; it < 4; ++it) {
    const int idx = it * 256 + tid;
    const int r = idx >> 3, c = idx & 7;
    const int j = i0 - 32 + r;
    uint4 kv_ = make_uint4(0u, 0u, 0u, 0u);
    uint4 vv = make_uint4(0u, 0u, 0u, 0u);
    if (j >= 0 && j < 2048) {
      const bf16* base = qkv + (size_t)(b * 2048 + j) * 3072 + 1024 + h * 64 + c * 8;
      kv_ = *(const uint4*)base;
      vv = *(const uint4*)(base + 1024);
    }
    *(uint4*)&Ks[r * 72 + c * 8] = kv_;
    *(uint4*)&Vs[r * 72 + c * 8] = vv;
  }
  __syncthreads();

  // transpose V: Vs[t][d] -> Vt[d][t]  (reads uniform b128, writes 2-lane/bank)
#pragma unroll
  for (int it = 0; it < 4; ++it) {
    const int idx = it * 256 + tid;
    const int t = idx & 127, c = idx >> 7;
    bf16x8 v = *(const bf16x8*)&Vs[t * 72 + c * 8];
#pragma unroll
    for (int jj = 0; jj < 8; ++jj) Vt[(c * 8 + jj) * 136 + t] = v[jj];
  }
  __syncthreads();

  // S = Q(16x64) @ Kwin(128x64)^T : 8 n-tiles x 2 k-steps
  floatx4 accS[8] = {};
#pragma unroll
  for (int nt = 0; nt < 8; ++nt)
#pragma unroll
    for (int ks = 0; ks < 2; ++ks) {
      bf16x8 bk = *(const bf16x8*)&Ks[(nt * 16 + n0) * 72 + ks * 32 + quad * 8];
      accS[nt] = __builtin_amdgcn_mfma_f32_16x16x32_bf16(aq[ks], bk, accS[nt], 0, 0, 0);
    }

  // scale + band mask + softmax (rows live across the 16 lanes of a quad)
  float mrow[4] = {-1e30f, -1e30f, -1e30f, -1e30f};
#pragma unroll
  for (int nt = 0; nt < 8; ++nt)
#pragma unroll
    for (int r = 0; r < 4; ++r) {
      const int q64 = wave * 16 + quad * 4 + r;
      const int t = nt * 16 + n0;
      float s = accS[nt][r] * 0.125f;  // 1/sqrt(64)
      if (t < q64 || t >= q64 + 64) s = -1e30f;
      accS[nt][r] = s;
      mrow[r] = fmaxf(mrow[r], s);
    }
#pragma unroll
  for (int off = 1; off < 16; off <<= 1)
#pragma unroll
    for (int r = 0; r < 4; ++r)
      mrow[r] = fmaxf(mrow[r], __shfl_xor(mrow[r], off));
  float lrow[4] = {0.f, 0.f, 0.f, 0.f};
#pragma unroll
  for (int nt = 0; nt < 8; ++nt)
#pragma unroll
    for (int r = 0; r < 4; ++r) {
      const float e = __expf(accS[nt][r] - mrow[r]);
      accS[nt][r] = e;
      lrow[r] += e;
    }
#pragma unroll
  for (int off = 1; off < 16; off <<= 1)
#pragma unroll
    for (int r = 0; r < 4; ++r) lrow[r] += __shfl_xor(lrow[r], off);

  // P (C-layout) -> LDS A-layout; per-wave region of VsPs (Vs dead after barrier)
  bf16* Pw = &VsPs[wave * 16 * 136];
#pragma unroll
  for (int r = 0; r < 4; ++r) {
    const float inv = 1.f / lrow[r];
#pragma unroll
    for (int nt = 0; nt < 8; ++nt)
      Pw[(quad * 4 + r) * 136 + nt * 16 + n0] = (bf16)(accS[nt][r] * inv);
  }

  // O = P(16x128) @ V(128x64): 4 k-steps x 4 d-tiles, all b128 frag reads
  floatx4 accO[4] = {};
#pragma unroll
  for (int kt = 0; kt < 4; ++kt) {
    bf16x8 ap = *(const bf16x8*)&Pw[n0 * 136 + kt * 32 + quad * 8];
#pragma unroll
    for (int dt = 0; dt < 4; ++dt) {
      bf16x8 bv = *(const bf16x8*)&Vt[(dt * 16 + n0) * 136 + kt * 32 + quad * 8];
      accO[dt] = __builtin_amdgcn_mfma_f32_16x16x32_bf16(ap, bv, accO[dt], 0, 0, 0);
    }
  }
#pragma unroll
  for (int dt = 0; dt < 4; ++dt)
#pragma unroll
    for (int r = 0; r < 4; ++r) {
      const int q64 = wave * 16 + quad * 4 + r;
      aout[(size_t)(b * 2048 + i0 + q64) * 1024 + h * 64 + dt * 16 + n0] =
          (bf16)accO[dt][r];
    }
}

// ---------------- launch -------------------------------------------------------
// ws layout (40 MB total):
//   [0,   8MB) xbf (4096x1024 bf16)   -- reused as attnout after GEMM1
//   [8,  14MB) wqkv bf16 (3072x1024, rows = [Wq;Wk;Wv])
//   [14, 16MB) wob  bf16 (1024x1024)
//   [16, 40MB) qkv  bf16 (4096x3072, row = [Q|K|V])
extern "C" void kernel_launch(void* const* d_in, const int* in_sizes, int n_in,
                              void* d_out, int out_size, void* d_ws, size_t ws_size,
                              hipStream_t stream) {
  const float* x = (const float*)d_in[0];
  const float* wq = (const float*)d_in[1];
  const float* wk = (const float*)d_in[2];
  const float* wv = (const float*)d_in[3];
  const float* wo = (const float*)d_in[4];
  const float* bo = (const float*)d_in[5];
  char* ws = (char*)d_ws;
  bf16* xbf = (bf16*)(ws);
  bf16* wqkv = (bf16*)(ws + (8u << 20));
  bf16* wob = (bf16*)(ws + (14u << 20));
  bf16* qkv = (bf16*)(ws + (16u << 20));
  bf16* aout = xbf;  // xbf dead after GEMM1; stream-ordered reuse

  convert_kernel<<<8192, 256, 0, stream>>>(x, wq, wk, wv, wo, xbf, wqkv, wob);
  // QKV projection: (4096 x 3072) = xbf(4096x1024) @ wqkv^T
  // 256x192 tile -> grid (16,16) = 256 blocks = 1/CU; R9 adds 2-D XCD chunk
  gemm192_nt<<<dim3(16, 16), 512, 0, stream>>>(xbf, wqkv, qkv, 4096, 3072, 1024);
  attn_kernel<<<1024, 256, 0, stream>>>(qkv, aout);
  // output projection: (4096 x 1024) fp32 = aout @ wob^T + bo
  // 128x128 4-phase counted-vmcnt, grid (8,32) = 256 blocks = 1/CU
  gemm128_nt<<<dim3(8, 32), 512, 0, stream>>>(aout, wob, (float*)d_out, bo,
                                              4096, 1024, 1024);
}

// Round 10
// 142.026 us; speedup vs baseline: 1.0188x; 1.0188x over previous
//
#include <hip/hip_runtime.h>
#include <hip/hip_bf16.h>
#include <cstdint>

typedef __bf16 bf16;
typedef __bf16 bf16x4 __attribute__((ext_vector_type(4)));
typedef __bf16 bf16x8 __attribute__((ext_vector_type(8)));
typedef float floatx4 __attribute__((ext_vector_type(4)));

typedef __attribute__((address_space(1))) void as1_void;
typedef __attribute__((address_space(3))) void as3_void;

// async global->LDS, 16B per lane. LDS dest must be wave-uniform base + lane*16.
__device__ __forceinline__ void gld16(const void* g, void* l) {
#if __has_builtin(__builtin_amdgcn_global_load_lds)
  __builtin_amdgcn_global_load_lds((as1_void*)(uintptr_t)g, (as3_void*)l, 16, 0, 0);
#else
  *(uint4*)l = *(const uint4*)g;
#endif
}

// ---------------- fp32 -> bf16 conversion (x, Wq|Wk|Wv concat, Wo) -------------
__global__ __launch_bounds__(256) void convert_kernel(
    const float* __restrict__ x, const float* __restrict__ wq,
    const float* __restrict__ wk, const float* __restrict__ wv,
    const float* __restrict__ wo, bf16* __restrict__ xbf,
    bf16* __restrict__ wqkv, bf16* __restrict__ wob) {
  int i = blockIdx.x * 256 + threadIdx.x;  // one float4 (4 elems) per thread
  const float* src;
  bf16* dst;
  int off;
  if (i < 1048576) {            // x: 4,194,304 elems
    src = x; dst = xbf; off = i;
  } else if (i < 1310720) {     // Wq
    src = wq; dst = wqkv; off = i - 1048576;
  } else if (i < 1572864) {     // Wk
    src = wk; dst = wqkv + 1048576; off = i - 1310720;
  } else if (i < 1835008) {     // Wv
    src = wv; dst = wqkv + 2097152; off = i - 1572864;
  } else {                      // Wo
    src = wo; dst = wob; off = i - 1835008;
  }
  float4 v = ((const float4*)src)[off];
  bf16x4 o;
  o[0] = (bf16)v.x; o[1] = (bf16)v.y; o[2] = (bf16)v.z; o[3] = (bf16)v.w;
  ((bf16x4*)dst)[off] = o;
}

// ---------------- 256x192 8-phase NT GEMM (T2+T3+T4+T5), bf16 out --------------
// Tile 256(M) x 192(N), BK=64 -> grid (16,16) = 256 blocks = EXACTLY 1/CU.
// 512 threads = 8 waves (2M x 4N), wave tile 128 x 48 (3 n-frags).
// LDS 112 KiB: buf{0,1} x [A 32K (4 units) | B 24K (3 units)]; a staging UNIT
// is 64 rows x 64 cols bf16 = 8 KiB = 1 gld16/thread. Swizzle: byte col slot s
// at row r holds global chunk s^(r&7), write-side on the global source and
// read-side on ds_read.
// Liveness ledger (buf0 tile T): B last read ph2, A last read ph3 ->
//   (T+2).B staged ph3/ph4, (T+2).A staged ph5..ph7; buf1: B last ph6, A ph7
//   -> (T+3).B0 ph7, rest ph8; (T+1).A1/A3 staged ph1/ph2.
// W1 (end ph4): vmcnt(3); final iter vmcnt(0). W2 (end ph8): vmcnt(5).
// Verified R6/R7/R8 (151.3 / 143.8 / 143.0 us totals, refcheck passed).
// Block mapping: DEFAULT dispatch order. XCD-locality swizzles tried three
// times (R2 1-D, R9 2-D here; R2 1-D on old GEMM2): ALL <= 0 on this
// L3-resident pipeline (matches m160). Do not re-add.
#define BAR asm volatile("s_barrier" ::: "memory")
#define LGKM0                                         \
  do {                                                \
    asm volatile("s_waitcnt lgkmcnt(0)" ::: "memory");\
    __builtin_amdgcn_sched_barrier(0);                \
  } while (0)

// stage one 64x64 unit of operand op (0=A,1=B), unit u, K-tile t, into buf
#define STAGEU(buf, op, u, t)                                                  \
  gld16(((op) ? Bb : Ab) + (size_t)(u) * 64 * Kb + (size_t)(t) * 128 + rowOff, \
        lds + (buf) * 57344 + (op) * 32768 + (u) * 8192 + tid * 16)

#define LDA_(buf, mh)                                                          \
  do {                                                                         \
    _Pragma("unroll") for (int q = 0; q < 4; ++q)                              \
      _Pragma("unroll") for (int ks = 0; ks < 2; ++ks)                         \
        aR[q][ks] = *(const bf16x8*)(lds + (buf) * 57344 +                     \
            (wm * 2 + (mh)) * 8192 + (q * 16 + n0) * 128 +                     \
            ((ks * 64 + quad * 16) ^ swz));                                    \
  } while (0)

#define LDB_(buf, g)                                                           \
  do {                                                                         \
    _Pragma("unroll") for (int j = 0; j < ((g) ? 1 : 2); ++j)                  \
      _Pragma("unroll") for (int ks = 0; ks < 2; ++ks) {                       \
        const int ni_ = (g) ? 2 : j;                                           \
        const int row_ = wn * 48 + ni_ * 16 + n0;                              \
        bR[ni_][ks] = *(const bf16x8*)(lds + (buf) * 57344 + 32768 +           \
            (row_ >> 6) * 8192 + (row_ & 63) * 128 +                           \
            ((ks * 64 + quad * 16) ^ swz));                                    \
      }                                                                        \
  } while (0)

#define MMg0(mh)                                                               \
  do {                                                                         \
    __builtin_amdgcn_s_setprio(1);                                             \
    _Pragma("unroll") for (int q = 0; q < 4; ++q)                              \
      _Pragma("unroll") for (int j = 0; j < 2; ++j)                            \
        _Pragma("unroll") for (int ks = 0; ks < 2; ++ks)                       \
          acc[(mh) * 4 + q][j] = __builtin_amdgcn_mfma_f32_16x16x32_bf16(      \
              aR[q][ks], bR[j][ks], acc[(mh) * 4 + q][j], 0, 0, 0);            \
    __builtin_amdgcn_s_setprio(0);                                             \
  } while (0)

#define MMg1(mh)                                                               \
  do {                                                                         \
    __builtin_amdgcn_s_setprio(1);                                             \
    _Pragma("unroll") for (int q = 0; q < 4; ++q)                              \
      _Pragma("unroll") for (int ks = 0; ks < 2; ++ks)                         \
        acc[(mh) * 4 + q][2] = __builtin_amdgcn_mfma_f32_16x16x32_bf16(        \
            aR[q][ks], bR[2][ks], acc[(mh) * 4 + q][2], 0, 0, 0);              \
    __builtin_amdgcn_s_setprio(0);                                             \
  } while (0)

__global__ __launch_bounds__(512, 2) void gemm192_nt(
    const bf16* __restrict__ A, const bf16* __restrict__ Bm,
    bf16* __restrict__ C, int M, int N, int K) {
  __shared__ __attribute__((aligned(16))) char lds[114688];
  const int tid = threadIdx.x;
  const int lane = tid & 63, wave = tid >> 6;
  const int quad = lane >> 4, n0 = lane & 15;
  const int wm = wave >> 2, wn = wave & 3;
  const int swz = (n0 & 7) << 4;
  const size_t Kb = (size_t)K * 2;  // row stride in bytes
  const char* Ab = (const char*)(A + (size_t)blockIdx.y * 256 * K);
  const char* Bb = (const char*)(Bm + (size_t)blockIdx.x * 192 * K);
  const int srow = tid >> 3;
  const size_t rowOff = (size_t)srow * Kb + (size_t)(16 * ((tid & 7) ^ (srow & 7)));

  floatx4 acc[8][3] = {};
  bf16x8 aR[4][2];     // current A m-half (4 m-frags x 2 k-steps)
  bf16x8 bR[3][2];     // all 3 n-frags x 2 k-steps

  const int NT = K >> 6;   // 64-wide K-tiles (even)
  const int NI = K >> 7;   // iterations (2 tiles each)

  // prologue: tile0 full (7 units) -> buf0; tile1 {B0,B1,B2,A0,A2} -> buf1
  STAGEU(0, 0, 0, 0); STAGEU(0, 0, 1, 0); STAGEU(0, 0, 2, 0); STAGEU(0, 0, 3, 0);
  STAGEU(0, 1, 0, 0); STAGEU(0, 1, 1, 0); STAGEU(0, 1, 2, 0);
  STAGEU(1, 1, 0, 1); STAGEU(1, 1, 1, 1); STAGEU(1, 1, 2, 1);
  STAGEU(1, 0, 0, 1); STAGEU(1, 0, 2, 1);
  asm volatile("s_waitcnt vmcnt(5)" ::: "memory");  // tile0's 7 units landed
  BAR;

  for (int i = 0; i < NI; ++i) {
    const int T = 2 * i;
    const bool s2 = (T + 2 < NT);   // == s3 (NT even)
    // ---- K-tile T from buf0 ----
    LDB_(0, 0); LDA_(0, 0);
    STAGEU(1, 0, 1, T + 1);                               // (T+1).A1
    BAR; LGKM0; MMg0(0); BAR;
    LDB_(0, 1);
    STAGEU(1, 0, 3, T + 1);                               // (T+1).A3
    BAR; LGKM0; MMg1(0); BAR;
    LDA_(0, 1);
    if (s2) { STAGEU(0, 1, 0, T + 2); STAGEU(0, 1, 1, T + 2); }  // (T+2).B0,B1
    BAR; LGKM0; MMg0(1); BAR;
    if (s2) STAGEU(0, 1, 2, T + 2);                       // (T+2).B2
    BAR; MMg1(1);
    if (i + 1 < NI) { asm volatile("s_waitcnt vmcnt(3)" ::: "memory"); }
    else            { asm volatile("s_waitcnt vmcnt(0)" ::: "memory"); }
    BAR;
    // ---- K-tile T+1 from buf1 ----
    LDB_(1, 0); LDA_(1, 0);
    if (s2) { STAGEU(0, 0, 0, T + 2); STAGEU(0, 0, 2, T + 2); }  // (T+2).A0,A2
    BAR; LGKM0; MMg0(0); BAR;
    LDB_(1, 1);
    if (s2) STAGEU(0, 0, 1, T + 2);                       // (T+2).A1
    BAR; LGKM0; MMg1(0); BAR;
    LDA_(1, 1);
    if (s2) { STAGEU(0, 0, 3, T + 2); STAGEU(1, 1, 0, T + 3); }  // (T+2).A3,(T+3).B0
    BAR; LGKM0; MMg0(1); BAR;
    if (s2) { STAGEU(1, 1, 1, T + 3); STAGEU(1, 1, 2, T + 3);    // (T+3).B1,B2
              STAGEU(1, 0, 0, T + 3); STAGEU(1, 0, 2, T + 3); }  // (T+3).A0,A2
    BAR; MMg1(1);
    asm volatile("s_waitcnt vmcnt(5)" ::: "memory");
    BAR;
  }

  const int rowBase = blockIdx.y * 256 + wm * 128 + quad * 4;
  const int colBase = blockIdx.x * 192 + wn * 48 + n0;
#pragma unroll
  for (int mi = 0; mi < 8; ++mi)
#pragma unroll
    for (int ni = 0; ni < 3; ++ni)
#pragma unroll
      for (int r = 0; r < 4; ++r)
        C[(size_t)(rowBase + mi * 16 + r) * N + colBase + ni * 16] =
            (bf16)acc[mi][ni][r];
}

#undef STAGEU
#undef LDA_
#undef LDB_
#undef MMg0
#undef MMg1

// ---------------- 128x128 4-phase NT GEMM, fp32+bias out (output proj) ---------
// Tile 128x128, BK=64 -> grid (8,32) = 256 blocks = 1/CU. 512 threads = 8 waves
// (2M x 4N), wave tile 64x32. 4 phases/iteration (2 per K-tile, 8 MFMA each),
// counted-vmcnt discipline. Verified R8 (143.0 us total, refcheck passed).
// Liveness ledger (unit = 64x64 = 8 KiB = 1 gld16/thread):
//   reads: ph1 {B0,B1 frags + A mh0}, MM(mh0); ph2 {A mh1}, MM(mh1).
//   stages: ph1 (T+1).{A0,A1,B1}; ph2 (T+2).{B0,B1}; ph3 (T+2).{A0,A1};
//           ph4 (T+3).{B0}.
//   W1 (end ph2): vmcnt(2) proves (T+1) landed (final iter: vmcnt(0)).
//   W2 (end ph4): vmcnt(1) proves (T+2) landed.
//   Prologue: 5 ops; vmcnt(1). NT=16 even -> s2 == s3.
// XCD-chunk: 32 ids/XCD = {4 A-panels (1MB) + whole wob (2MB)} = 3MB < L2.
// (kept: measured within noise vs R1 but footprint arithmetic is sound and
//  R7/R8 verified with it in place)
#define STAGE2(buf, op, u, t)                                                  \
  gld16(((op) ? Bb : Ab) + (size_t)(u) * 64 * Kb + (size_t)(t) * 128 + rowOff, \
        lds + (buf) * 32768 + (op) * 16384 + (u) * 8192 + tid * 16)

#define LDA2(buf, mh)                                                          \
  do {                                                                         \
    _Pragma("unroll") for (int qq = 0; qq < 2; ++qq)                           \
      _Pragma("unroll") for (int ks = 0; ks < 2; ++ks)                         \
        aR[qq][ks] = *(const bf16x8*)(lds + (buf) * 32768 + wm * 8192 +        \
            (((mh) * 2 + qq) * 16 + n0) * 128 + ((ks * 64 + quad * 16) ^ swz));\
  } while (0)

#define LDB2(buf, j)                                                           \
  do {                                                                         \
    _Pragma("unroll") for (int ks = 0; ks < 2; ++ks)                           \
      bR[j][ks] = *(const bf16x8*)(lds + (buf) * 32768 + 16384 +               \
          (wn >> 1) * 8192 + ((wn & 1) * 32 + (j) * 16 + n0) * 128 +           \
          ((ks * 64 + quad * 16) ^ swz));                                      \
  } while (0)

#define MM2(mh, nh)                                                            \
  do {                                                                         \
    __builtin_amdgcn_s_setprio(1);                                             \
    _Pragma("unroll") for (int qq = 0; qq < 2; ++qq)                           \
      _Pragma("unroll") for (int ks = 0; ks < 2; ++ks)                         \
        acc[(mh) * 2 + qq][nh] = __builtin_amdgcn_mfma_f32_16x16x32_bf16(      \
            aR[qq][ks], bR[nh][ks], acc[(mh) * 2 + qq][nh], 0, 0, 0);          \
    __builtin_amdgcn_s_setprio(0);                                             \
  } while (0)

__global__ __launch_bounds__(512, 2) void gemm128_nt(
    const bf16* __restrict__ A, const bf16* __restrict__ Bm,
    float* __restrict__ Cf, const float* __restrict__ bias,
    int M, int N, int K) {
  __shared__ __attribute__((aligned(16))) char lds[65536];
  const int tid = threadIdx.x;
  const int lane = tid & 63, wave = tid >> 6;
  const int quad = lane >> 4, n0 = lane & 15;
  const int wm = wave >> 2, wn = wave & 3;
  const int swz = (n0 & 7) << 4;
  const size_t Kb = (size_t)K * 2;
  // XCD-chunked bijective swizzle (nwg = 256, multiple of 8)
  const int nwg = gridDim.x * gridDim.y;
  const int nid = blockIdx.y * gridDim.x + blockIdx.x;
  int sid = nid;
  if ((nwg & 7) == 0) sid = (nid & 7) * (nwg >> 3) + (nid >> 3);
  const int bx = sid % gridDim.x, by = sid / gridDim.x;
  const char* Ab = (const char*)(A + (size_t)by * 128 * K);
  const char* Bb = (const char*)(Bm + (size_t)bx * 128 * K);
  const int srow = tid >> 3;
  const size_t rowOff = (size_t)srow * Kb + (size_t)(16 * ((tid & 7) ^ (srow & 7)));

  floatx4 acc[4][2] = {};
  bf16x8 aR[2][2];   // current m-half frags (2 q x 2 ks)
  bf16x8 bR[2][2];   // both n-frags x 2 ks

  const int NT = K >> 6;   // 16
  const int NI = K >> 7;   // 8

  // prologue: tile0 {A0,A1,B0,B1} -> buf0; tile1 {B0} -> buf1
  STAGE2(0, 0, 0, 0); STAGE2(0, 0, 1, 0); STAGE2(0, 1, 0, 0); STAGE2(0, 1, 1, 0);
  STAGE2(1, 1, 0, 1);
  asm volatile("s_waitcnt vmcnt(1)" ::: "memory");  // tile0 landed
  BAR;

  for (int i = 0; i < NI; ++i) {
    const int T = 2 * i;
    const bool s2 = (T + 2 < NT);   // == s3 (NT even)
    // ---- K-tile T from buf0 (2 fat phases) ----
    LDB2(0, 0); LDB2(0, 1); LDA2(0, 0);
    STAGE2(1, 0, 0, T + 1); STAGE2(1, 0, 1, T + 1);   // (T+1).A0,A1
    STAGE2(1, 1, 1, T + 1);                           // (T+1).B1
    BAR; LGKM0; MM2(0, 0); MM2(0, 1); BAR;
    LDA2(0, 1);
    if (s2) { STAGE2(0, 1, 0, T + 2); STAGE2(0, 1, 1, T + 2); }  // (T+2).B0,B1
    BAR; LGKM0; MM2(1, 0); MM2(1, 1);
    if (i + 1 < NI) { asm volatile("s_waitcnt vmcnt(2)" ::: "memory"); }
    else            { asm volatile("s_waitcnt vmcnt(0)" ::: "memory"); }
    BAR;
    // ---- K-tile T+1 from buf1 (2 fat phases) ----
    LDB2(1, 0); LDB2(1, 1); LDA2(1, 0);
    if (s2) { STAGE2(0, 0, 0, T + 2); STAGE2(0, 0, 1, T + 2); }  // (T+2).A0,A1
    BAR; LGKM0; MM2(0, 0); MM2(0, 1); BAR;
    LDA2(1, 1);
    if (s2) STAGE2(1, 1, 0, T + 3);                   // (T+3).B0
    BAR; LGKM0; MM2(1, 0); MM2(1, 1);
    asm volatile("s_waitcnt vmcnt(1)" ::: "memory");
    BAR;
  }

  const int rowBase = by * 128 + wm * 64 + quad * 4;
  const int colBase = bx * 128 + wn * 32 + n0;
#pragma unroll
  for (int ni = 0; ni < 2; ++ni) {
    const float badd = bias[colBase + ni * 16];
#pragma unroll
    for (int mi = 0; mi < 4; ++mi)
#pragma unroll
      for (int r = 0; r < 4; ++r)
        Cf[(size_t)(rowBase + mi * 16 + r) * N + colBase + ni * 16] =
            acc[mi][ni][r] + badd;
  }
}

#undef BAR
#undef LGKM0
#undef STAGE2
#undef LDA2
#undef LDB2
#undef MM2

// ---------------- sliding-window attention ------------------------------------
// block = (b, h, 64-query tile); 4 waves, wave w owns queries [w*16, w*16+16).
// Key window rows t=0..127 <-> j = i0-32+t; out-of-range rows are zero
// (matches reference zero-padding: score 0 participates in softmax, V adds 0).
// LDS strides chosen so every frag access is <=2 lanes/bank (free, m136):
//   Ks stride 72 (144 B), Vt stride 136 (272 B), Ps stride 136.
__global__ __launch_bounds__(256) void attn_kernel(const bf16* __restrict__ qkv,
                                                   bf16* __restrict__ aout) {
  __shared__ __attribute__((aligned(16))) bf16 Ks[128 * 72];
  __shared__ __attribute__((aligned(16))) bf16 VsPs[128 * 72];  // Vs, then Ps
  __shared__ __attribute__((aligned(16))) bf16 Vt[64 * 136];
  const int bid = blockIdx.x;
  const int b = bid >> 9;            // 512 blocks per batch (16 heads x 32 tiles)
  const int h = (bid >> 5) & 15;
  const int i0 = (bid & 31) * 64;
  const int tid = threadIdx.x;
  const int wave = tid >> 6, lane = tid & 63;
  const int quad = lane >> 4, n0 = lane & 15;
  bf16* Vs = VsPs;

  // Q fragments straight from global, issued EARLY so HBM/L2 latency hides
  // under the K/V staging + transpose (consumed only after the barriers).
  bf16x8 aq[2];
#pragma unroll
  for (int ks = 0; ks < 2; ++ks)
    aq[ks] = *(const bf16x8*)(qkv +
        (size_t)(b * 2048 + i0 + wave * 16 + n0) * 3072 + h * 64 + ks * 32 + quad * 8);

  // stage K and V windows: 128 rows x 8 16B-chunks each, zero out-of-range
#pragma unroll
  for (int it = 0; it < 4; ++it) {
    const int idx = it * 256 + tid;
    const int r = idx >> 3, c = idx & 7;
    const int j = i0 - 32 + r;
    uint4 kv_ = make_uint4(0u, 0u, 0u, 0u);
    uint4 vv = make_uint4(0u, 0u, 0u, 0u);
    if (j >= 0 && j < 2048) {
      const bf16* base = qkv + (size_t)(b * 2048 + j) * 3072 + 1024 + h * 64 + c * 8;
      kv_ = *(const uint4*)base;
      vv = *(const uint4*)(base + 1024);
    }
    *(uint4*)&Ks[r * 72 + c * 8] = kv_;
    *(uint4*)&Vs[r * 72 + c * 8] = vv;
  }
  __syncthreads();

  // transpose V: Vs[t][d] -> Vt[d][t]  (reads uniform b128, writes 2-lane/bank)
#pragma unroll
  for (int it = 0; it < 4; ++it) {
    const int idx = it * 256 + tid;
    const int t = idx & 127, c = idx >> 7;
    bf16x8 v = *(const bf16x8*)&Vs[t * 72 + c * 8];
#pragma unroll
    for (int jj = 0; jj < 8; ++jj) Vt[(c * 8 + jj) * 136 + t] = v[jj];
  }
  __syncthreads();

  // S = Q(16x64) @ Kwin(128x64)^T : 8 n-tiles x 2 k-steps
  floatx4 accS[8] = {};
#pragma unroll
  for (int nt = 0; nt < 8; ++nt)
#pragma unroll
    for (int ks = 0; ks < 2; ++ks) {
      bf16x8 bk = *(const bf16x8*)&Ks[(nt * 16 + n0) * 72 + ks * 32 + quad * 8];
      accS[nt] = __builtin_amdgcn_mfma_f32_16x16x32_bf16(aq[ks], bk, accS[nt], 0, 0, 0);
    }

  // scale + band mask + softmax (rows live across the 16 lanes of a quad)
  float mrow[4] = {-1e30f, -1e30f, -1e30f, -1e30f};
#pragma unroll
  for (int nt = 0; nt < 8; ++nt)
#pragma unroll
    for (int r = 0; r < 4; ++r) {
      const int q64 = wave * 16 + quad * 4 + r;
      const int t = nt * 16 + n0;
      float s = accS[nt][r] * 0.125f;  // 1/sqrt(64)
      if (t < q64 || t >= q64 + 64) s = -1e30f;
      accS[nt][r] = s;
      mrow[r] = fmaxf(mrow[r], s);
    }
#pragma unroll
  for (int off = 1; off < 16; off <<= 1)
#pragma unroll
    for (int r = 0; r < 4; ++r)
      mrow[r] = fmaxf(mrow[r], __shfl_xor(mrow[r], off));
  float lrow[4] = {0.f, 0.f, 0.f, 0.f};
#pragma unroll
  for (int nt = 0; nt < 8; ++nt)
#pragma unroll
    for (int r = 0; r < 4; ++r) {
      const float e = __expf(accS[nt][r] - mrow[r]);
      accS[nt][r] = e;
      lrow[r] += e;
    }
#pragma unroll
  for (int off = 1; off < 16; off <<= 1)
#pragma unroll
    for (int r = 0; r < 4; ++r) lrow[r] += __shfl_xor(lrow[r], off);

  // P (C-layout) -> LDS A-layout; per-wave region of VsPs (Vs dead after barrier)
  bf16* Pw = &VsPs[wave * 16 * 136];
#pragma unroll
  for (int r = 0; r < 4; ++r) {
    const float inv = 1.f / lrow[r];
#pragma unroll
    for (int nt = 0; nt < 8; ++nt)
      Pw[(quad * 4 + r) * 136 + nt * 16 + n0] = (bf16)(accS[nt][r] * inv);
  }

  // O = P(16x128) @ V(128x64): 4 k-steps x 4 d-tiles, all b128 frag reads
  floatx4 accO[4] = {};
#pragma unroll
  for (int kt = 0; kt < 4; ++kt) {
    bf16x8 ap = *(const bf16x8*)&Pw[n0 * 136 + kt * 32 + quad * 8];
#pragma unroll
    for (int dt = 0; dt < 4; ++dt) {
      bf16x8 bv = *(const bf16x8*)&Vt[(dt * 16 + n0) * 136 + kt * 32 + quad * 8];
      accO[dt] = __builtin_amdgcn_mfma_f32_16x16x32_bf16(ap, bv, accO[dt], 0, 0, 0);
    }
  }
#pragma unroll
  for (int dt = 0; dt < 4; ++dt)
#pragma unroll
    for (int r = 0; r < 4; ++r) {
      const int q64 = wave * 16 + quad * 4 + r;
      aout[(size_t)(b * 2048 + i0 + q64) * 1024 + h * 64 + dt * 16 + n0] =
          (bf16)accO[dt][r];
    }
}

// ---------------- launch -------------------------------------------------------
// ws layout (40 MB total):
//   [0,   8MB) xbf (4096x1024 bf16)   -- reused as attnout after GEMM1
//   [8,  14MB) wqkv bf16 (3072x1024, rows = [Wq;Wk;Wv])
//   [14, 16MB) wob  bf16 (1024x1024)
//   [16, 40MB) qkv  bf16 (4096x3072, row = [Q|K|V])
extern "C" void kernel_launch(void* const* d_in, const int* in_sizes, int n_in,
                              void* d_out, int out_size, void* d_ws, size_t ws_size,
                              hipStream_t stream) {
  const float* x = (const float*)d_in[0];
  const float* wq = (const float*)d_in[1];
  const float* wk = (const float*)d_in[2];
  const float* wv = (const float*)d_in[3];
  const float* wo = (const float*)d_in[4];
  const float* bo = (const float*)d_in[5];
  char* ws = (char*)d_ws;
  bf16* xbf = (bf16*)(ws);
  bf16* wqkv = (bf16*)(ws + (8u << 20));
  bf16* wob = (bf16*)(ws + (14u << 20));
  bf16* qkv = (bf16*)(ws + (16u << 20));
  bf16* aout = xbf;  // xbf dead after GEMM1; stream-ordered reuse

  convert_kernel<<<8192, 256, 0, stream>>>(x, wq, wk, wv, wo, xbf, wqkv, wob);
  // QKV projection: (4096 x 3072) = xbf(4096x1024) @ wqkv^T
  // 256x192 tile -> grid (16,16) = 256 blocks = exactly 1 block/CU, 100% fill
  gemm192_nt<<<dim3(16, 16), 512, 0, stream>>>(xbf, wqkv, qkv, 4096, 3072, 1024);
  attn_kernel<<<1024, 256, 0, stream>>>(qkv, aout);
  // output projection: (4096 x 1024) fp32 = aout @ wob^T + bo
  // 128x128 4-phase counted-vmcnt, grid (8,32) = 256 blocks = 1/CU
  gemm128_nt<<<dim3(8, 32), 512, 0, stream>>>(aout, wob, (float*)d_out, bo,
                                              4096, 1024, 1024);
}